// Round 1
// baseline (1789.576 us; speedup 1.0000x reference)
//
#include <hip/hip_runtime.h>

#define BN_EPS 1e-5f

// ---------------- shared-memory union ----------------
struct FpsSm {
  float X[2048], Y[2048], Z[2048];
  float candV[2][4];
  int   candJ[2][4];
};
struct FeatSm {
  float W1s[256];        // folded layer-1 weights: [c][4] = a*w0,a*w1,a*w2, be-a*mean
  float h1s[128][68];    // padded rows (68 floats = 272B, 16B aligned)
  float stat[4][64][8];  // per-wave partial stats
};
union __align__(16) SMem { FpsSm fps; FeatSm feat; };

// ---------------- FPS (exact, matches jnp reference) ----------------
template<int NPTS>
__device__ void fps_body(const float* __restrict__ pts, float* __restrict__ ptsNext,
                         float* __restrict__ momNext, SMem* sm) {
  constexpr int R = NPTS / 256;
  constexpr int M = NPTS / 2;
  const int b    = blockIdx.x;
  const int tid  = threadIdx.x;
  const int lane = tid & 63;
  const int w    = tid >> 6;
  float* X = sm->fps.X; float* Y = sm->fps.Y; float* Z = sm->fps.Z;
  const float* p0 = pts + (size_t)b * NPTS * 3;

  float px[R], py[R], pz[R], mind[R];
#pragma unroll
  for (int i = 0; i < R; i++) {
    const int j = tid + 256 * i;
    const float x = p0[3*j], y = p0[3*j+1], z = p0[3*j+2];
    px[i] = x; py[i] = y; pz[i] = z;
    X[j] = x; Y[j] = y; Z[j] = z;
  }
  __syncthreads();

  float sx = X[0], sy = Y[0], sz = Z[0];
  // moments of selected points (for next level's layer-1 BN stats)
  float m0 = sx, m1 = sy, m2 = sz;
  float m3 = sx*sx, m4 = sy*sy, m5 = sz*sz, m6 = sx*sy, m7 = sx*sz, m8 = sy*sz;
  if (tid == 0) { float* o = ptsNext + (size_t)b * M * 3; o[0]=sx; o[1]=sy; o[2]=sz; }

  float bv = -1.0f; int bj = 0;
#pragma unroll
  for (int i = 0; i < R; i++) {
    const float dx = px[i]-sx, dy = py[i]-sy, dz = pz[i]-sz;
    const float d = __fadd_rn(__fadd_rn(__fmul_rn(dx,dx), __fmul_rn(dy,dy)), __fmul_rn(dz,dz));
    mind[i] = d;
    if (d > bv) { bv = d; bj = tid + 256*i; }   // strict > : first (lowest j) wins
  }

  for (int it = 1; it < M; ++it) {
    // intra-wave argmax butterfly, tie-break to lowest global index
#pragma unroll
    for (int off = 32; off >= 1; off >>= 1) {
      const float ov = __shfl_xor(bv, off);
      const int   oj = __shfl_xor(bj, off);
      if (ov > bv || (ov == bv && oj < bj)) { bv = ov; bj = oj; }
    }
    const int par = it & 1;                     // double-buffered candidate slots
    if (lane == 0) { sm->fps.candV[par][w] = bv; sm->fps.candJ[par][w] = bj; }
    __syncthreads();
    float cv = sm->fps.candV[par][0]; int cj = sm->fps.candJ[par][0];
#pragma unroll
    for (int q = 1; q < 4; q++) {
      const float v = sm->fps.candV[par][q]; const int j = sm->fps.candJ[par][q];
      if (v > cv || (v == cv && j < cj)) { cv = v; cj = j; }
    }
    sx = X[cj]; sy = Y[cj]; sz = Z[cj];
    if (tid == 0) { float* o = ptsNext + ((size_t)b * M + it) * 3; o[0]=sx; o[1]=sy; o[2]=sz; }
    m0 += sx; m1 += sy; m2 += sz;
    m3 = fmaf(sx,sx,m3); m4 = fmaf(sy,sy,m4); m5 = fmaf(sz,sz,m5);
    m6 = fmaf(sx,sy,m6); m7 = fmaf(sx,sz,m7); m8 = fmaf(sy,sz,m8);

    bv = -1.0f; bj = 0;
#pragma unroll
    for (int i = 0; i < R; i++) {
      const float dx = px[i]-sx, dy = py[i]-sy, dz = pz[i]-sz;
      const float d = __fadd_rn(__fadd_rn(__fmul_rn(dx,dx), __fmul_rn(dy,dy)), __fmul_rn(dz,dz));
      const float mv = fminf(mind[i], d);
      mind[i] = mv;
      if (mv > bv) { bv = mv; bj = tid + 256*i; }
    }
  }
  if (tid == 0) {
    float* o = momNext + b * 9;
    o[0]=m0; o[1]=m1; o[2]=m2; o[3]=m3; o[4]=m4; o[5]=m5; o[6]=m6; o[7]=m7; o[8]=m8;
  }
}

// ---------------- feature pass: h1=relu(BN1(x@w1)), y2=h1@w2; stats+extremes ----------------
template<int NPTS>
__device__ void featB_body(const float* __restrict__ pts, const float* __restrict__ W1f,
                           const float* __restrict__ w2, float* __restrict__ partialsB,
                           int fbid, SMem* sm) {
  const int tid  = threadIdx.x;
  const int lane = tid & 63;
  const int w    = tid >> 6;
  constexpr int BPB = NPTS / 256;       // blocks per batch
  const int b = fbid / BPB;
  const size_t pbase = (size_t)b * NPTS + (size_t)(fbid % BPB) * 256;

  float* W1s = sm->feat.W1s;
  W1s[tid < 256 ? tid : 0] = W1f[tid < 256 ? tid : 0];
  __syncthreads();

  // per-lane layer-2 weight columns: channel `lane` and `lane+64`
  float wA[64], wB[64];
#pragma unroll
  for (int k = 0; k < 64; k++) { wA[k] = w2[k*128 + lane]; wB[k] = w2[k*128 + 64 + lane]; }

  float sA=0.f, qA=0.f, sB=0.f, qB=0.f;
  float mxA=-1e30f, mnA=1e30f, mxB=-1e30f, mnB=1e30f;

  for (int r = 0; r < 2; r++) {
    __syncthreads();                     // protect h1s overwrite vs previous round's reads
    if (tid < 128) {                     // phase A: compute h1 for 128 points
      const float* pp = pts + (pbase + (size_t)r*128 + tid) * 3;
      const float x = pp[0], y = pp[1], z = pp[2];
#pragma unroll
      for (int k = 0; k < 64; k += 4) {
        float4 hv;
        { const float4 wf = *reinterpret_cast<const float4*>(&W1s[4*(k  )]);
          hv.x = fmaxf(0.f, fmaf(x,wf.x, fmaf(y,wf.y, fmaf(z,wf.z, wf.w)))); }
        { const float4 wf = *reinterpret_cast<const float4*>(&W1s[4*(k+1)]);
          hv.y = fmaxf(0.f, fmaf(x,wf.x, fmaf(y,wf.y, fmaf(z,wf.z, wf.w)))); }
        { const float4 wf = *reinterpret_cast<const float4*>(&W1s[4*(k+2)]);
          hv.z = fmaxf(0.f, fmaf(x,wf.x, fmaf(y,wf.y, fmaf(z,wf.z, wf.w)))); }
        { const float4 wf = *reinterpret_cast<const float4*>(&W1s[4*(k+3)]);
          hv.w = fmaxf(0.f, fmaf(x,wf.x, fmaf(y,wf.y, fmaf(z,wf.z, wf.w)))); }
        *reinterpret_cast<float4*>(&sm->feat.h1s[tid][k]) = hv;
      }
    }
    __syncthreads();
    // phase B: wave w consumes rows [w*32, w*32+32)
    const int row0 = w * 32;
    for (int p = row0; p < row0 + 32; ++p) {
      float ya = 0.f, yb = 0.f;
#pragma unroll
      for (int k = 0; k < 64; k += 4) {
        const float4 hv = *reinterpret_cast<const float4*>(&sm->feat.h1s[p][k]);
        ya = fmaf(hv.x, wA[k  ], ya);  yb = fmaf(hv.x, wB[k  ], yb);
        ya = fmaf(hv.y, wA[k+1], ya);  yb = fmaf(hv.y, wB[k+1], yb);
        ya = fmaf(hv.z, wA[k+2], ya);  yb = fmaf(hv.z, wB[k+2], yb);
        ya = fmaf(hv.w, wA[k+3], ya);  yb = fmaf(hv.w, wB[k+3], yb);
      }
      sA += ya; qA = fmaf(ya,ya,qA); mxA = fmaxf(mxA,ya); mnA = fminf(mnA,ya);
      sB += yb; qB = fmaf(yb,yb,qB); mxB = fmaxf(mxB,yb); mnB = fminf(mnB,yb);
    }
  }

  float4* st = reinterpret_cast<float4*>(&sm->feat.stat[w][lane][0]);
  st[0] = make_float4(sA,qA,mxA,mnA);
  st[1] = make_float4(sB,qB,mxB,mnB);
  __syncthreads();
  if (w == 0) {
    float4 aA = *reinterpret_cast<float4*>(&sm->feat.stat[0][lane][0]);
    float4 aB = *reinterpret_cast<float4*>(&sm->feat.stat[0][lane][4]);
#pragma unroll
    for (int q = 1; q < 4; q++) {
      const float4 cA = *reinterpret_cast<float4*>(&sm->feat.stat[q][lane][0]);
      const float4 cB = *reinterpret_cast<float4*>(&sm->feat.stat[q][lane][4]);
      aA.x += cA.x; aA.y += cA.y; aA.z = fmaxf(aA.z,cA.z); aA.w = fminf(aA.w,cA.w);
      aB.x += cB.x; aB.y += cB.y; aB.z = fmaxf(aB.z,cB.z); aB.w = fminf(aB.w,cB.w);
    }
    float* pb = partialsB + (size_t)fbid * 512;
    pb[0*128 +      lane] = aA.x; pb[1*128 +      lane] = aA.y;
    pb[2*128 +      lane] = aA.z; pb[3*128 +      lane] = aA.w;
    pb[0*128 + 64 + lane] = aB.x; pb[1*128 + 64 + lane] = aB.y;
    pb[2*128 + 64 + lane] = aB.z; pb[3*128 + 64 + lane] = aB.w;
  }
}

// ---------------- fused level kernel: blocks 0..63 = FPS, rest = feature pass ----------------
template<int NPTS, bool HASFPS>
__global__ __launch_bounds__(256, 2) void level_main(const float* __restrict__ pts,
    const float* __restrict__ W1f, const float* __restrict__ w2,
    float* __restrict__ partialsB, float* __restrict__ ptsNext, float* __restrict__ momNext) {
  __shared__ SMem sm;
  if (HASFPS && blockIdx.x < 64) { fps_body<NPTS>(pts, ptsNext, momNext, &sm); return; }
  const int fbid = HASFPS ? (int)blockIdx.x - 64 : (int)blockIdx.x;
  featB_body<NPTS>(pts, W1f, w2, partialsB, fbid, &sm);
}

// ---------------- level-0 moment reduction (9 moments of xyz) ----------------
__global__ __launch_bounds__(256) void mom0_kernel(const float* __restrict__ pts,
                                                   float* __restrict__ mp) {
  __shared__ float red[256];
  const int tid = threadIdx.x;
  float acc[9] = {0,0,0,0,0,0,0,0,0};
#pragma unroll
  for (int i = 0; i < 4; i++) {
    const size_t j = (size_t)blockIdx.x * 1024 + (size_t)i * 256 + tid;
    const float x = pts[3*j], y = pts[3*j+1], z = pts[3*j+2];
    acc[0]+=x; acc[1]+=y; acc[2]+=z;
    acc[3]=fmaf(x,x,acc[3]); acc[4]=fmaf(y,y,acc[4]); acc[5]=fmaf(z,z,acc[5]);
    acc[6]=fmaf(x,y,acc[6]); acc[7]=fmaf(x,z,acc[7]); acc[8]=fmaf(y,z,acc[8]);
  }
  for (int k = 0; k < 9; k++) {
    red[tid] = acc[k]; __syncthreads();
    for (int s = 128; s > 0; s >>= 1) { if (tid < s) red[tid] += red[tid+s]; __syncthreads(); }
    if (tid == 0) mp[blockIdx.x*9 + k] = red[0];
    __syncthreads();
  }
}

// ---------------- fold layer-1 BN into weights via moments ----------------
__global__ __launch_bounds__(64) void fin1_kernel(const float* __restrict__ mom, int npart,
    float Pinv, const float* __restrict__ w1, const float* __restrict__ g1,
    const float* __restrict__ be1, float* __restrict__ W1f) {
  __shared__ float M[9];
  const int t = threadIdx.x;
  if (t < 9) { float s = 0.f; for (int i = 0; i < npart; i++) s += mom[i*9 + t]; M[t] = s; }
  __syncthreads();
  const float w0 = w1[0*64 + t], w1_ = w1[1*64 + t], w2_ = w1[2*64 + t];
  const float mean = (w0*M[0] + w1_*M[1] + w2_*M[2]) * Pinv;
  const float ey2  = (w0*w0*M[3] + w1_*w1_*M[4] + w2_*w2_*M[5]
                    + 2.f*(w0*w1_*M[6] + w0*w2_*M[7] + w1_*w2_*M[8])) * Pinv;
  const float var  = fmaxf(ey2 - mean*mean, 0.f);
  const float a    = g1[t] * rsqrtf(var + BN_EPS);
  float4 r; r.x = a*w0; r.y = a*w1_; r.z = a*w2_; r.w = fmaf(-a, mean, be1[t]);
  *reinterpret_cast<float4*>(&W1f[t*4]) = r;
}

// ---------------- layer-2 BN coefficients from per-block partial sums ----------------
__global__ __launch_bounds__(128) void f2a_kernel(const float* __restrict__ partialsB, int nb,
    float Pinv, const float* __restrict__ g2, const float* __restrict__ be2,
    float* __restrict__ a2c2) {
  const int ch = threadIdx.x;
  float s = 0.f, q = 0.f;
  for (int i = 0; i < nb; i++) {
    s += partialsB[(size_t)i*512 + ch];
    q += partialsB[(size_t)i*512 + 128 + ch];
  }
  const float mean = s * Pinv;
  const float var  = fmaxf(q * Pinv - mean*mean, 0.f);
  const float a    = g2[ch] * rsqrtf(var + BN_EPS);
  a2c2[ch] = a; a2c2[128 + ch] = fmaf(-a, mean, be2[ch]);
}

// ---------------- final: maxpool(relu(BN2(y2))) via extremes ----------------
__global__ __launch_bounds__(128) void f2b_kernel(const float* __restrict__ partialsB, int bpb,
    const float* __restrict__ a2c2, float* __restrict__ out, int lv) {
  const int b = blockIdx.x, ch = threadIdx.x;
  const float* pb = partialsB + (size_t)b * bpb * 512;
  const float a = a2c2[ch], c = a2c2[128 + ch];
  float mx = -1e30f, mn = 1e30f;
  for (int i = 0; i < bpb; i++) {
    mx = fmaxf(mx, pb[(size_t)i*512 + 256 + ch]);
    mn = fminf(mn, pb[(size_t)i*512 + 384 + ch]);
  }
  const float v = (a >= 0.f) ? mx : mn;
  out[b*384 + lv*128 + ch] = fmaxf(0.f, fmaf(a, v, c));
}

// ---------------- host launch ----------------
extern "C" void kernel_launch(void* const* d_in, const int* in_sizes, int n_in,
                              void* d_out, int out_size, void* d_ws, size_t ws_size,
                              hipStream_t stream) {
  const float* pts = (const float*)d_in[0];
  const float* w1  = (const float*)d_in[1];
  const float* g1  = (const float*)d_in[3];
  const float* be1 = (const float*)d_in[4];
  const float* w2  = (const float*)d_in[5];
  const float* g2  = (const float*)d_in[7];
  const float* be2 = (const float*)d_in[8];
  float* out = (float*)d_out;
  float* wsf = (float*)d_ws;

  float* pts1 = wsf;               // 64*1024*3 = 196608
  float* pts2 = pts1 + 196608;     // 64*512*3  =  98304
  float* W1f  = pts2 + 98304;      // 256
  float* a2c2 = W1f  + 256;        // 256
  float* momP = a2c2 + 256;        // 1152 (max of 128*9, 64*9)
  float* partB= momP + 1152;       // 512*512 = 262144

  // ---- level 0 (N=2048, P=131072) ----
  mom0_kernel<<<128, 256, 0, stream>>>(pts, momP);
  fin1_kernel<<<1, 64, 0, stream>>>(momP, 128, 1.f/131072.f, w1, g1, be1, W1f);
  level_main<2048, true><<<64 + 512, 256, 0, stream>>>(pts, W1f, w2, partB, pts1, momP);
  f2a_kernel<<<1, 128, 0, stream>>>(partB, 512, 1.f/131072.f, g2, be2, a2c2);
  f2b_kernel<<<64, 128, 0, stream>>>(partB, 8, a2c2, out, 0);

  // ---- level 1 (N=1024, P=65536) ----
  fin1_kernel<<<1, 64, 0, stream>>>(momP, 64, 1.f/65536.f, w1 + 192, g1 + 64, be1 + 64, W1f);
  level_main<1024, true><<<64 + 256, 256, 0, stream>>>(pts1, W1f, w2 + 8192, partB, pts2, momP);
  f2a_kernel<<<1, 128, 0, stream>>>(partB, 256, 1.f/65536.f, g2 + 128, be2 + 128, a2c2);
  f2b_kernel<<<64, 128, 0, stream>>>(partB, 4, a2c2, out, 1);

  // ---- level 2 (N=512, P=32768, no FPS) ----
  fin1_kernel<<<1, 64, 0, stream>>>(momP, 64, 1.f/32768.f, w1 + 384, g1 + 128, be1 + 128, W1f);
  level_main<512, false><<<128, 256, 0, stream>>>(pts2, W1f, w2 + 16384, partB, wsf, wsf);
  f2a_kernel<<<1, 128, 0, stream>>>(partB, 128, 1.f/32768.f, g2 + 256, be2 + 256, a2c2);
  f2b_kernel<<<64, 128, 0, stream>>>(partB, 2, a2c2, out, 2);
}

// Round 2
// 1311.745 us; speedup vs baseline: 1.3643x; 1.3643x over previous
//
#include <hip/hip_runtime.h>

#define BN_EPS 1e-5f

// ---------------- shared-memory union ----------------
struct FpsSm {
  uint4 slotK[2][4];   // per-wave candidate: {~j, dist_bits, x_bits, y_bits}
  float slotZ[2][4];
};
struct FeatSm {
  float W1s[256];        // folded layer-1 weights: [c][4] = a*w0,a*w1,a*w2, be-a*mean
  float h1s[128][68];    // padded rows (68 floats = 272B, 16B aligned)
  float stat[4][64][8];  // per-wave partial stats
};
union __align__(16) SMem { FpsSm fps; FeatSm feat; };

// ---------------- fast wave-wide max (DPP) ----------------
#if __has_builtin(__builtin_amdgcn_update_dpp) && __has_builtin(__builtin_amdgcn_readlane)
template<int CTRL>
__device__ __forceinline__ float dppmax(float x) {
  const int t = __builtin_amdgcn_update_dpp(0, __float_as_int(x), CTRL, 0xf, 0xf, true);
  return fmaxf(x, __int_as_float(t));
}
__device__ __forceinline__ float wave_max_f32(float x) {
  x = dppmax<0x111>(x);  // row_shr:1
  x = dppmax<0x112>(x);  // row_shr:2
  x = dppmax<0x114>(x);  // row_shr:4
  x = dppmax<0x118>(x);  // row_shr:8
  x = dppmax<0x142>(x);  // row_bcast15
  x = dppmax<0x143>(x);  // row_bcast31
  return __int_as_float(__builtin_amdgcn_readlane(__float_as_int(x), 63));
}
#else
__device__ __forceinline__ float wave_max_f32(float x) {
  for (int off = 32; off; off >>= 1) x = fmaxf(x, __shfl_xor(x, off));
  return x;
}
#endif

__device__ __forceinline__ int rdlane_i(int v, int l) {
  return __builtin_amdgcn_readlane(v, l);
}
__device__ __forceinline__ float rdlane_f(float v, int l) {
  return __int_as_float(__builtin_amdgcn_readlane(__float_as_int(v), l));
}

// ---------------- FPS (exact, matches jnp/np reference) ----------------
template<int NPTS>
__device__ void fps_body(const float* __restrict__ pts, float* __restrict__ ptsNext,
                         float* __restrict__ momNext, SMem* sm) {
  constexpr int R = NPTS / 256;
  constexpr int M = NPTS / 2;
  const int b    = blockIdx.x;
  const int tid  = threadIdx.x;
  const int lane = tid & 63;
  const int w    = tid >> 6;
  const float* p0 = pts + (size_t)b * NPTS * 3;

  float px[R], py[R], pz[R], mind[R];
#pragma unroll
  for (int i = 0; i < R; i++) {
    const int j = tid + 256 * i;
    px[i] = p0[3*j]; py[i] = p0[3*j+1]; pz[i] = p0[3*j+2];
  }

  float sx = p0[0], sy = p0[1], sz = p0[2];
  // moments of selected points (for next level's layer-1 BN stats)
  float m0 = sx, m1 = sy, m2 = sz;
  float m3 = sx*sx, m4 = sy*sy, m5 = sz*sz, m6 = sx*sy, m7 = sx*sz, m8 = sy*sz;
  if (tid == 0) { float* o = ptsNext + (size_t)b * M * 3; o[0]=sx; o[1]=sy; o[2]=sz; }

  // per-lane best carries value, global index, and the point's coords
  float bv = -1.0f, bx = 0.f, by = 0.f, bz = 0.f; int bj = 0;
#pragma unroll
  for (int i = 0; i < R; i++) {
    const float dx = px[i]-sx, dy = py[i]-sy, dz = pz[i]-sz;
    const float d = __fadd_rn(__fadd_rn(__fmul_rn(dx,dx), __fmul_rn(dy,dy)), __fmul_rn(dz,dz));
    mind[i] = d;
    if (d > bv) { bv = d; bj = tid + 256*i; bx = px[i]; by = py[i]; bz = pz[i]; }
  }

  for (int it = 1; it < M; ++it) {
    // --- wave-level: value max via DPP, then pick owner lane ---
    const float smax = wave_max_f32(bv);
    unsigned long long mk = __ballot(bv == smax);
    int winl = (int)(__ffsll((unsigned long long)mk) - 1);
    if (__popcll(mk) > 1) {            // exact ties (rare): first-index wins
      int jj = (bv == smax) ? bj : 0x7fffffff;
      for (int off = 32; off; off >>= 1) jj = min(jj, __shfl_xor(jj, off));
      mk = __ballot((bv == smax) && (bj == jj));
      winl = (int)(__ffsll((unsigned long long)mk) - 1);
    }
    const unsigned wj = (unsigned)rdlane_i(bj, winl);
    const float wx = rdlane_f(bx, winl);
    const float wy = rdlane_f(by, winl);
    const float wz = rdlane_f(bz, winl);

    // --- cross-wave: one LDS slot per wave, single barrier, double-buffered ---
    const int par = it & 1;
    if (lane == 0) {
      sm->fps.slotK[par][w] = make_uint4(~wj, __float_as_uint(smax),
                                         __float_as_uint(wx), __float_as_uint(wy));
      sm->fps.slotZ[par][w] = wz;
    }
    __syncthreads();
    uint4 kk = sm->fps.slotK[par][0];
    unsigned long long bk = ((unsigned long long)kk.y << 32) | kk.x;
    float nx = __uint_as_float(kk.z), ny = __uint_as_float(kk.w);
    float nz = sm->fps.slotZ[par][0];
#pragma unroll
    for (int q = 1; q < 4; q++) {
      const uint4 kq = sm->fps.slotK[par][q];
      const unsigned long long kqk = ((unsigned long long)kq.y << 32) | kq.x;
      if (kqk > bk) {
        bk = kqk;
        nx = __uint_as_float(kq.z); ny = __uint_as_float(kq.w);
        nz = sm->fps.slotZ[par][q];
      }
    }
    sx = nx; sy = ny; sz = nz;
    if (tid == 0) { float* o = ptsNext + ((size_t)b * M + it) * 3; o[0]=sx; o[1]=sy; o[2]=sz; }
    m0 += sx; m1 += sy; m2 += sz;
    m3 = fmaf(sx,sx,m3); m4 = fmaf(sy,sy,m4); m5 = fmaf(sz,sz,m5);
    m6 = fmaf(sx,sy,m6); m7 = fmaf(sx,sz,m7); m8 = fmaf(sy,sz,m8);

    // --- distance update + per-lane argmax scan ---
    bv = -1.0f; bj = 0;
#pragma unroll
    for (int i = 0; i < R; i++) {
      const float dx = px[i]-sx, dy = py[i]-sy, dz = pz[i]-sz;
      const float d = __fadd_rn(__fadd_rn(__fmul_rn(dx,dx), __fmul_rn(dy,dy)), __fmul_rn(dz,dz));
      const float mv = fminf(mind[i], d);
      mind[i] = mv;
      if (mv > bv) { bv = mv; bj = tid + 256*i; bx = px[i]; by = py[i]; bz = pz[i]; }
    }
  }
  if (tid == 0) {
    float* o = momNext + b * 9;
    o[0]=m0; o[1]=m1; o[2]=m2; o[3]=m3; o[4]=m4; o[5]=m5; o[6]=m6; o[7]=m7; o[8]=m8;
  }
}

// ---------------- feature pass: h1=relu(BN1(x@w1)), y2=h1@w2; stats+extremes ----------------
template<int NPTS>
__device__ void featB_body(const float* __restrict__ pts, const float* __restrict__ W1f,
                           const float* __restrict__ w2, float* __restrict__ partialsB,
                           int fbid, SMem* sm) {
  const int tid  = threadIdx.x;
  const int lane = tid & 63;
  const int w    = tid >> 6;
  constexpr int BPB = NPTS / 256;       // blocks per batch
  const int b = fbid / BPB;
  const size_t pbase = (size_t)b * NPTS + (size_t)(fbid % BPB) * 256;

  float* W1s = sm->feat.W1s;
  W1s[tid < 256 ? tid : 0] = W1f[tid < 256 ? tid : 0];
  __syncthreads();

  // per-lane layer-2 weight columns: channel `lane` and `lane+64`
  float wA[64], wB[64];
#pragma unroll
  for (int k = 0; k < 64; k++) { wA[k] = w2[k*128 + lane]; wB[k] = w2[k*128 + 64 + lane]; }

  float sA=0.f, qA=0.f, sB=0.f, qB=0.f;
  float mxA=-1e30f, mnA=1e30f, mxB=-1e30f, mnB=1e30f;

  for (int r = 0; r < 2; r++) {
    __syncthreads();                     // protect h1s overwrite vs previous round's reads
    if (tid < 128) {                     // phase A: compute h1 for 128 points
      const float* pp = pts + (pbase + (size_t)r*128 + tid) * 3;
      const float x = pp[0], y = pp[1], z = pp[2];
#pragma unroll
      for (int k = 0; k < 64; k += 4) {
        float4 hv;
        { const float4 wf = *reinterpret_cast<const float4*>(&W1s[4*(k  )]);
          hv.x = fmaxf(0.f, fmaf(x,wf.x, fmaf(y,wf.y, fmaf(z,wf.z, wf.w)))); }
        { const float4 wf = *reinterpret_cast<const float4*>(&W1s[4*(k+1)]);
          hv.y = fmaxf(0.f, fmaf(x,wf.x, fmaf(y,wf.y, fmaf(z,wf.z, wf.w)))); }
        { const float4 wf = *reinterpret_cast<const float4*>(&W1s[4*(k+2)]);
          hv.z = fmaxf(0.f, fmaf(x,wf.x, fmaf(y,wf.y, fmaf(z,wf.z, wf.w)))); }
        { const float4 wf = *reinterpret_cast<const float4*>(&W1s[4*(k+3)]);
          hv.w = fmaxf(0.f, fmaf(x,wf.x, fmaf(y,wf.y, fmaf(z,wf.z, wf.w)))); }
        *reinterpret_cast<float4*>(&sm->feat.h1s[tid][k]) = hv;
      }
    }
    __syncthreads();
    // phase B: wave w consumes rows [w*32, w*32+32)
    const int row0 = w * 32;
    for (int p = row0; p < row0 + 32; ++p) {
      float ya = 0.f, yb = 0.f;
#pragma unroll
      for (int k = 0; k < 64; k += 4) {
        const float4 hv = *reinterpret_cast<const float4*>(&sm->feat.h1s[p][k]);
        ya = fmaf(hv.x, wA[k  ], ya);  yb = fmaf(hv.x, wB[k  ], yb);
        ya = fmaf(hv.y, wA[k+1], ya);  yb = fmaf(hv.y, wB[k+1], yb);
        ya = fmaf(hv.z, wA[k+2], ya);  yb = fmaf(hv.z, wB[k+2], yb);
        ya = fmaf(hv.w, wA[k+3], ya);  yb = fmaf(hv.w, wB[k+3], yb);
      }
      sA += ya; qA = fmaf(ya,ya,qA); mxA = fmaxf(mxA,ya); mnA = fminf(mnA,ya);
      sB += yb; qB = fmaf(yb,yb,qB); mxB = fmaxf(mxB,yb); mnB = fminf(mnB,yb);
    }
  }

  float4* st = reinterpret_cast<float4*>(&sm->feat.stat[w][lane][0]);
  st[0] = make_float4(sA,qA,mxA,mnA);
  st[1] = make_float4(sB,qB,mxB,mnB);
  __syncthreads();
  if (w == 0) {
    float4 aA = *reinterpret_cast<float4*>(&sm->feat.stat[0][lane][0]);
    float4 aB = *reinterpret_cast<float4*>(&sm->feat.stat[0][lane][4]);
#pragma unroll
    for (int q = 1; q < 4; q++) {
      const float4 cA = *reinterpret_cast<float4*>(&sm->feat.stat[q][lane][0]);
      const float4 cB = *reinterpret_cast<float4*>(&sm->feat.stat[q][lane][4]);
      aA.x += cA.x; aA.y += cA.y; aA.z = fmaxf(aA.z,cA.z); aA.w = fminf(aA.w,cA.w);
      aB.x += cB.x; aB.y += cB.y; aB.z = fmaxf(aB.z,cB.z); aB.w = fminf(aB.w,cB.w);
    }
    float* pb = partialsB + (size_t)fbid * 512;
    pb[0*128 +      lane] = aA.x; pb[1*128 +      lane] = aA.y;
    pb[2*128 +      lane] = aA.z; pb[3*128 +      lane] = aA.w;
    pb[0*128 + 64 + lane] = aB.x; pb[1*128 + 64 + lane] = aB.y;
    pb[2*128 + 64 + lane] = aB.z; pb[3*128 + 64 + lane] = aB.w;
  }
}

// ---------------- fused level kernel: blocks 0..63 = FPS, rest = feature pass ----------------
template<int NPTS, bool HASFPS>
__global__ __launch_bounds__(256, 2) void level_main(const float* __restrict__ pts,
    const float* __restrict__ W1f, const float* __restrict__ w2,
    float* __restrict__ partialsB, float* __restrict__ ptsNext, float* __restrict__ momNext) {
  __shared__ SMem sm;
  if (HASFPS && blockIdx.x < 64) { fps_body<NPTS>(pts, ptsNext, momNext, &sm); return; }
  const int fbid = HASFPS ? (int)blockIdx.x - 64 : (int)blockIdx.x;
  featB_body<NPTS>(pts, W1f, w2, partialsB, fbid, &sm);
}

// ---------------- level-0 moment reduction (9 moments of xyz) ----------------
__global__ __launch_bounds__(256) void mom0_kernel(const float* __restrict__ pts,
                                                   float* __restrict__ mp) {
  __shared__ float red[256];
  const int tid = threadIdx.x;
  float acc[9] = {0,0,0,0,0,0,0,0,0};
#pragma unroll
  for (int i = 0; i < 4; i++) {
    const size_t j = (size_t)blockIdx.x * 1024 + (size_t)i * 256 + tid;
    const float x = pts[3*j], y = pts[3*j+1], z = pts[3*j+2];
    acc[0]+=x; acc[1]+=y; acc[2]+=z;
    acc[3]=fmaf(x,x,acc[3]); acc[4]=fmaf(y,y,acc[4]); acc[5]=fmaf(z,z,acc[5]);
    acc[6]=fmaf(x,y,acc[6]); acc[7]=fmaf(x,z,acc[7]); acc[8]=fmaf(y,z,acc[8]);
  }
  for (int k = 0; k < 9; k++) {
    red[tid] = acc[k]; __syncthreads();
    for (int s = 128; s > 0; s >>= 1) { if (tid < s) red[tid] += red[tid+s]; __syncthreads(); }
    if (tid == 0) mp[blockIdx.x*9 + k] = red[0];
    __syncthreads();
  }
}

// ---------------- fold layer-1 BN into weights via moments ----------------
__global__ __launch_bounds__(64) void fin1_kernel(const float* __restrict__ mom, int npart,
    float Pinv, const float* __restrict__ w1, const float* __restrict__ g1,
    const float* __restrict__ be1, float* __restrict__ W1f) {
  __shared__ float M[9];
  const int t = threadIdx.x;
  if (t < 9) { float s = 0.f; for (int i = 0; i < npart; i++) s += mom[i*9 + t]; M[t] = s; }
  __syncthreads();
  const float w0 = w1[0*64 + t], w1_ = w1[1*64 + t], w2_ = w1[2*64 + t];
  const float mean = (w0*M[0] + w1_*M[1] + w2_*M[2]) * Pinv;
  const float ey2  = (w0*w0*M[3] + w1_*w1_*M[4] + w2_*w2_*M[5]
                    + 2.f*(w0*w1_*M[6] + w0*w2_*M[7] + w1_*w2_*M[8])) * Pinv;
  const float var  = fmaxf(ey2 - mean*mean, 0.f);
  const float a    = g1[t] * rsqrtf(var + BN_EPS);
  float4 r; r.x = a*w0; r.y = a*w1_; r.z = a*w2_; r.w = fmaf(-a, mean, be1[t]);
  *reinterpret_cast<float4*>(&W1f[t*4]) = r;
}

// ---------------- layer-2 BN coefficients from per-block partial sums ----------------
__global__ __launch_bounds__(128) void f2a_kernel(const float* __restrict__ partialsB, int nb,
    float Pinv, const float* __restrict__ g2, const float* __restrict__ be2,
    float* __restrict__ a2c2) {
  const int ch = threadIdx.x;
  float s = 0.f, q = 0.f;
  for (int i = 0; i < nb; i++) {
    s += partialsB[(size_t)i*512 + ch];
    q += partialsB[(size_t)i*512 + 128 + ch];
  }
  const float mean = s * Pinv;
  const float var  = fmaxf(q * Pinv - mean*mean, 0.f);
  const float a    = g2[ch] * rsqrtf(var + BN_EPS);
  a2c2[ch] = a; a2c2[128 + ch] = fmaf(-a, mean, be2[ch]);
}

// ---------------- final: maxpool(relu(BN2(y2))) via extremes ----------------
__global__ __launch_bounds__(128) void f2b_kernel(const float* __restrict__ partialsB, int bpb,
    const float* __restrict__ a2c2, float* __restrict__ out, int lv) {
  const int b = blockIdx.x, ch = threadIdx.x;
  const float* pb = partialsB + (size_t)b * bpb * 512;
  const float a = a2c2[ch], c = a2c2[128 + ch];
  float mx = -1e30f, mn = 1e30f;
  for (int i = 0; i < bpb; i++) {
    mx = fmaxf(mx, pb[(size_t)i*512 + 256 + ch]);
    mn = fminf(mn, pb[(size_t)i*512 + 384 + ch]);
  }
  const float v = (a >= 0.f) ? mx : mn;
  out[b*384 + lv*128 + ch] = fmaxf(0.f, fmaf(a, v, c));
}

// ---------------- host launch ----------------
extern "C" void kernel_launch(void* const* d_in, const int* in_sizes, int n_in,
                              void* d_out, int out_size, void* d_ws, size_t ws_size,
                              hipStream_t stream) {
  const float* pts = (const float*)d_in[0];
  const float* w1  = (const float*)d_in[1];
  const float* g1  = (const float*)d_in[3];
  const float* be1 = (const float*)d_in[4];
  const float* w2  = (const float*)d_in[5];
  const float* g2  = (const float*)d_in[7];
  const float* be2 = (const float*)d_in[8];
  float* out = (float*)d_out;
  float* wsf = (float*)d_ws;

  float* pts1 = wsf;               // 64*1024*3 = 196608
  float* pts2 = pts1 + 196608;     // 64*512*3  =  98304
  float* W1f  = pts2 + 98304;      // 256
  float* a2c2 = W1f  + 256;        // 256
  float* momP = a2c2 + 256;        // 1152 (max of 128*9, 64*9)
  float* partB= momP + 1152;       // 512*512 = 262144

  // ---- level 0 (N=2048, P=131072) ----
  mom0_kernel<<<128, 256, 0, stream>>>(pts, momP);
  fin1_kernel<<<1, 64, 0, stream>>>(momP, 128, 1.f/131072.f, w1, g1, be1, W1f);
  level_main<2048, true><<<64 + 512, 256, 0, stream>>>(pts, W1f, w2, partB, pts1, momP);
  f2a_kernel<<<1, 128, 0, stream>>>(partB, 512, 1.f/131072.f, g2, be2, a2c2);
  f2b_kernel<<<64, 128, 0, stream>>>(partB, 8, a2c2, out, 0);

  // ---- level 1 (N=1024, P=65536) ----
  fin1_kernel<<<1, 64, 0, stream>>>(momP, 64, 1.f/65536.f, w1 + 192, g1 + 64, be1 + 64, W1f);
  level_main<1024, true><<<64 + 256, 256, 0, stream>>>(pts1, W1f, w2 + 8192, partB, pts2, momP);
  f2a_kernel<<<1, 128, 0, stream>>>(partB, 256, 1.f/65536.f, g2 + 128, be2 + 128, a2c2);
  f2b_kernel<<<64, 128, 0, stream>>>(partB, 4, a2c2, out, 1);

  // ---- level 2 (N=512, P=32768, no FPS) ----
  fin1_kernel<<<1, 64, 0, stream>>>(momP, 64, 1.f/32768.f, w1 + 384, g1 + 128, be1 + 128, W1f);
  level_main<512, false><<<128, 256, 0, stream>>>(pts2, W1f, w2 + 16384, partB, wsf, wsf);
  f2a_kernel<<<1, 128, 0, stream>>>(partB, 128, 1.f/32768.f, g2 + 256, be2 + 256, a2c2);
  f2b_kernel<<<64, 128, 0, stream>>>(partB, 2, a2c2, out, 2);
}

// Round 3
// 1202.321 us; speedup vs baseline: 1.4884x; 1.0910x over previous
//
#include <hip/hip_runtime.h>

#define BN_EPS 1e-5f

// ---------------- shared-memory union ----------------
struct FpsSm {
  uint4 slotK[2][4];   // per-wave candidate: {~j, dist_bits, x_bits, y_bits}
  float slotZ[2][4];
  float sel[3 * 1024]; // selected points buffered in LDS (xyz interleaved), flushed at end
};
struct FeatSm {
  float W1s[256];        // folded layer-1 weights: [c][4] = a*w0,a*w1,a*w2, be-a*mean
  float h1s[128][68];    // padded rows (68 floats = 272B, 16B aligned)
  float stat[4][64][8];  // per-wave partial stats
};
union __align__(16) SMem { FpsSm fps; FeatSm feat; };

// ---------------- fast wave-wide max (DPP) ----------------
#if __has_builtin(__builtin_amdgcn_update_dpp) && __has_builtin(__builtin_amdgcn_readlane)
template<int CTRL>
__device__ __forceinline__ float dppmax(float x) {
  const int t = __builtin_amdgcn_update_dpp(0, __float_as_int(x), CTRL, 0xf, 0xf, true);
  return fmaxf(x, __int_as_float(t));
}
__device__ __forceinline__ float wave_max_f32(float x) {
  x = dppmax<0x111>(x);  // row_shr:1
  x = dppmax<0x112>(x);  // row_shr:2
  x = dppmax<0x114>(x);  // row_shr:4
  x = dppmax<0x118>(x);  // row_shr:8
  x = dppmax<0x142>(x);  // row_bcast15
  x = dppmax<0x143>(x);  // row_bcast31
  return __int_as_float(__builtin_amdgcn_readlane(__float_as_int(x), 63));
}
#else
__device__ __forceinline__ float wave_max_f32(float x) {
  for (int off = 32; off; off >>= 1) x = fmaxf(x, __shfl_xor(x, off));
  return x;
}
#endif

__device__ __forceinline__ int rdlane_i(int v, int l) {
  return __builtin_amdgcn_readlane(v, l);
}
__device__ __forceinline__ float rdlane_f(float v, int l) {
  return __int_as_float(__builtin_amdgcn_readlane(__float_as_int(v), l));
}

// ---------------- FPS (exact, matches jnp/np reference) ----------------
template<int NPTS>
__device__ void fps_body(const float* __restrict__ pts, float* __restrict__ ptsNext,
                         float* __restrict__ momNext, SMem* sm) {
  constexpr int R = NPTS / 256;
  constexpr int M = NPTS / 2;
  const int b    = blockIdx.x;
  const int tid  = threadIdx.x;
  const int lane = tid & 63;
  const int w    = tid >> 6;
  const float* p0 = pts + (size_t)b * NPTS * 3;
  float* sel = sm->fps.sel;

  float px[R], py[R], pz[R], mind[R];
#pragma unroll
  for (int i = 0; i < R; i++) {
    const int j = tid + 256 * i;
    px[i] = p0[3*j]; py[i] = p0[3*j+1]; pz[i] = p0[3*j+2];
  }

  float sx = p0[0], sy = p0[1], sz = p0[2];
  // moments of selected points (for next level's layer-1 BN stats)
  float m0 = sx, m1 = sy, m2 = sz;
  float m3 = sx*sx, m4 = sy*sy, m5 = sz*sz, m6 = sx*sy, m7 = sx*sz, m8 = sy*sz;
  if (tid == 0) { sel[0] = sx; sel[1] = sy; sel[2] = sz; }

  // per-lane best carries value, global index, and the point's coords
  float bv = -1.0f, bx = 0.f, by = 0.f, bz = 0.f; int bj = 0;
#pragma unroll
  for (int i = 0; i < R; i++) {
    const float dx = px[i]-sx, dy = py[i]-sy, dz = pz[i]-sz;
    const float d = __fadd_rn(__fadd_rn(__fmul_rn(dx,dx), __fmul_rn(dy,dy)), __fmul_rn(dz,dz));
    mind[i] = d;
    if (d > bv) { bv = d; bj = tid + 256*i; bx = px[i]; by = py[i]; bz = pz[i]; }
  }

  for (int it = 1; it < M; ++it) {
    // --- wave-level: value max via DPP, then pick owner lane ---
    const float smax = wave_max_f32(bv);
    unsigned long long mk = __ballot(bv == smax);
    int winl = (int)(__ffsll((unsigned long long)mk) - 1);
    if (__popcll(mk) > 1) {            // exact ties (rare): first-index wins
      int jj = (bv == smax) ? bj : 0x7fffffff;
      for (int off = 32; off; off >>= 1) jj = min(jj, __shfl_xor(jj, off));
      mk = __ballot((bv == smax) && (bj == jj));
      winl = (int)(__ffsll((unsigned long long)mk) - 1);
    }
    const unsigned wj = (unsigned)rdlane_i(bj, winl);
    const float wx = rdlane_f(bx, winl);
    const float wy = rdlane_f(by, winl);
    const float wz = rdlane_f(bz, winl);

    // --- cross-wave: one LDS slot per wave, single barrier, double-buffered ---
    const int par = it & 1;
    if (lane == 0) {
      sm->fps.slotK[par][w] = make_uint4(~wj, __float_as_uint(smax),
                                         __float_as_uint(wx), __float_as_uint(wy));
      sm->fps.slotZ[par][w] = wz;
    }
    __syncthreads();
    // tree-combine the 4 wave candidates
    const uint4 k0 = sm->fps.slotK[par][0], k1 = sm->fps.slotK[par][1];
    const uint4 k2 = sm->fps.slotK[par][2], k3 = sm->fps.slotK[par][3];
    const float z0 = sm->fps.slotZ[par][0], z1 = sm->fps.slotZ[par][1];
    const float z2 = sm->fps.slotZ[par][2], z3 = sm->fps.slotZ[par][3];
    const unsigned long long K0 = ((unsigned long long)k0.y << 32) | k0.x;
    const unsigned long long K1 = ((unsigned long long)k1.y << 32) | k1.x;
    const unsigned long long K2 = ((unsigned long long)k2.y << 32) | k2.x;
    const unsigned long long K3 = ((unsigned long long)k3.y << 32) | k3.x;
    const bool a01 = K1 > K0, a23 = K3 > K2;
    const unsigned long long Ka = a01 ? K1 : K0, Kb = a23 ? K3 : K2;
    const uint4 kA = a01 ? k1 : k0, kB = a23 ? k3 : k2;
    const float zA = a01 ? z1 : z0, zB = a23 ? z3 : z2;
    const bool ab = Kb > Ka;
    const uint4 kW = ab ? kB : kA;
    sx = __uint_as_float(kW.z); sy = __uint_as_float(kW.w); sz = ab ? zB : zA;

    if (tid == 0) { sel[3*it] = sx; sel[3*it+1] = sy; sel[3*it+2] = sz; }
    m0 += sx; m1 += sy; m2 += sz;
    m3 = fmaf(sx,sx,m3); m4 = fmaf(sy,sy,m4); m5 = fmaf(sz,sz,m5);
    m6 = fmaf(sx,sy,m6); m7 = fmaf(sx,sz,m7); m8 = fmaf(sy,sz,m8);

    // --- distance update + per-lane argmax scan ---
    bv = -1.0f; bj = 0;
#pragma unroll
    for (int i = 0; i < R; i++) {
      const float dx = px[i]-sx, dy = py[i]-sy, dz = pz[i]-sz;
      const float d = __fadd_rn(__fadd_rn(__fmul_rn(dx,dx), __fmul_rn(dy,dy)), __fmul_rn(dz,dz));
      const float mv = fminf(mind[i], d);
      mind[i] = mv;
      if (mv > bv) { bv = mv; bj = tid + 256*i; bx = px[i]; by = py[i]; bz = pz[i]; }
    }
  }
  if (tid == 0) {
    float* o = momNext + b * 9;
    o[0]=m0; o[1]=m1; o[2]=m2; o[3]=m3; o[4]=m4; o[5]=m5; o[6]=m6; o[7]=m7; o[8]=m8;
  }
  // bulk coalesced flush of selected points (LDS -> global), once
  __syncthreads();
  float* o = ptsNext + (size_t)b * M * 3;
#pragma unroll
  for (int e = tid; e < 3 * M; e += 256) o[e] = sel[e];
}

// ---------------- feature pass: h1=relu(BN1(x@w1)), y2=h1@w2; stats+extremes ----------------
template<int NPTS>
__device__ void featB_body(const float* __restrict__ pts, const float* __restrict__ W1f,
                           const float* __restrict__ w2, float* __restrict__ partialsB,
                           int fbid, SMem* sm) {
  const int tid  = threadIdx.x;
  const int lane = tid & 63;
  const int w    = tid >> 6;
  constexpr int BPB = NPTS / 256;       // blocks per batch
  const int b = fbid / BPB;
  const size_t pbase = (size_t)b * NPTS + (size_t)(fbid % BPB) * 256;

  float* W1s = sm->feat.W1s;
  W1s[tid < 256 ? tid : 0] = W1f[tid < 256 ? tid : 0];
  __syncthreads();

  // per-lane layer-2 weight columns: channel `lane` and `lane+64`
  float wA[64], wB[64];
#pragma unroll
  for (int k = 0; k < 64; k++) { wA[k] = w2[k*128 + lane]; wB[k] = w2[k*128 + 64 + lane]; }

  float sA=0.f, qA=0.f, sB=0.f, qB=0.f;
  float mxA=-1e30f, mnA=1e30f, mxB=-1e30f, mnB=1e30f;

  for (int r = 0; r < 2; r++) {
    __syncthreads();                     // protect h1s overwrite vs previous round's reads
    if (tid < 128) {                     // phase A: compute h1 for 128 points
      const float* pp = pts + (pbase + (size_t)r*128 + tid) * 3;
      const float x = pp[0], y = pp[1], z = pp[2];
#pragma unroll
      for (int k = 0; k < 64; k += 4) {
        float4 hv;
        { const float4 wf = *reinterpret_cast<const float4*>(&W1s[4*(k  )]);
          hv.x = fmaxf(0.f, fmaf(x,wf.x, fmaf(y,wf.y, fmaf(z,wf.z, wf.w)))); }
        { const float4 wf = *reinterpret_cast<const float4*>(&W1s[4*(k+1)]);
          hv.y = fmaxf(0.f, fmaf(x,wf.x, fmaf(y,wf.y, fmaf(z,wf.z, wf.w)))); }
        { const float4 wf = *reinterpret_cast<const float4*>(&W1s[4*(k+2)]);
          hv.z = fmaxf(0.f, fmaf(x,wf.x, fmaf(y,wf.y, fmaf(z,wf.z, wf.w)))); }
        { const float4 wf = *reinterpret_cast<const float4*>(&W1s[4*(k+3)]);
          hv.w = fmaxf(0.f, fmaf(x,wf.x, fmaf(y,wf.y, fmaf(z,wf.z, wf.w)))); }
        *reinterpret_cast<float4*>(&sm->feat.h1s[tid][k]) = hv;
      }
    }
    __syncthreads();
    // phase B: wave w consumes rows [w*32, w*32+32)
    const int row0 = w * 32;
    for (int p = row0; p < row0 + 32; ++p) {
      float ya = 0.f, yb = 0.f;
#pragma unroll
      for (int k = 0; k < 64; k += 4) {
        const float4 hv = *reinterpret_cast<const float4*>(&sm->feat.h1s[p][k]);
        ya = fmaf(hv.x, wA[k  ], ya);  yb = fmaf(hv.x, wB[k  ], yb);
        ya = fmaf(hv.y, wA[k+1], ya);  yb = fmaf(hv.y, wB[k+1], yb);
        ya = fmaf(hv.z, wA[k+2], ya);  yb = fmaf(hv.z, wB[k+2], yb);
        ya = fmaf(hv.w, wA[k+3], ya);  yb = fmaf(hv.w, wB[k+3], yb);
      }
      sA += ya; qA = fmaf(ya,ya,qA); mxA = fmaxf(mxA,ya); mnA = fminf(mnA,ya);
      sB += yb; qB = fmaf(yb,yb,qB); mxB = fmaxf(mxB,yb); mnB = fminf(mnB,yb);
    }
  }

  float4* st = reinterpret_cast<float4*>(&sm->feat.stat[w][lane][0]);
  st[0] = make_float4(sA,qA,mxA,mnA);
  st[1] = make_float4(sB,qB,mxB,mnB);
  __syncthreads();
  if (w == 0) {
    float4 aA = *reinterpret_cast<float4*>(&sm->feat.stat[0][lane][0]);
    float4 aB = *reinterpret_cast<float4*>(&sm->feat.stat[0][lane][4]);
#pragma unroll
    for (int q = 1; q < 4; q++) {
      const float4 cA = *reinterpret_cast<float4*>(&sm->feat.stat[q][lane][0]);
      const float4 cB = *reinterpret_cast<float4*>(&sm->feat.stat[q][lane][4]);
      aA.x += cA.x; aA.y += cA.y; aA.z = fmaxf(aA.z,cA.z); aA.w = fminf(aA.w,cA.w);
      aB.x += cB.x; aB.y += cB.y; aB.z = fmaxf(aB.z,cB.z); aB.w = fminf(aB.w,cB.w);
    }
    float* pb = partialsB + (size_t)fbid * 512;
    pb[0*128 +      lane] = aA.x; pb[1*128 +      lane] = aA.y;
    pb[2*128 +      lane] = aA.z; pb[3*128 +      lane] = aA.w;
    pb[0*128 + 64 + lane] = aB.x; pb[1*128 + 64 + lane] = aB.y;
    pb[2*128 + 64 + lane] = aB.z; pb[3*128 + 64 + lane] = aB.w;
  }
}

// ---------------- fused level kernel: blocks 0..63 = FPS, rest = feature pass ----------------
template<int NPTS, bool HASFPS>
__global__ __launch_bounds__(256, 2) void level_main(const float* __restrict__ pts,
    const float* __restrict__ W1f, const float* __restrict__ w2,
    float* __restrict__ partialsB, float* __restrict__ ptsNext, float* __restrict__ momNext) {
  __shared__ SMem sm;
  if (HASFPS && blockIdx.x < 64) { fps_body<NPTS>(pts, ptsNext, momNext, &sm); return; }
  const int fbid = HASFPS ? (int)blockIdx.x - 64 : (int)blockIdx.x;
  featB_body<NPTS>(pts, W1f, w2, partialsB, fbid, &sm);
}

// ---------------- level-0 moment reduction (9 moments of xyz) ----------------
__global__ __launch_bounds__(256) void mom0_kernel(const float* __restrict__ pts,
                                                   float* __restrict__ mp) {
  __shared__ float red[256];
  const int tid = threadIdx.x;
  float acc[9] = {0,0,0,0,0,0,0,0,0};
#pragma unroll
  for (int i = 0; i < 4; i++) {
    const size_t j = (size_t)blockIdx.x * 1024 + (size_t)i * 256 + tid;
    const float x = pts[3*j], y = pts[3*j+1], z = pts[3*j+2];
    acc[0]+=x; acc[1]+=y; acc[2]+=z;
    acc[3]=fmaf(x,x,acc[3]); acc[4]=fmaf(y,y,acc[4]); acc[5]=fmaf(z,z,acc[5]);
    acc[6]=fmaf(x,y,acc[6]); acc[7]=fmaf(x,z,acc[7]); acc[8]=fmaf(y,z,acc[8]);
  }
  for (int k = 0; k < 9; k++) {
    red[tid] = acc[k]; __syncthreads();
    for (int s = 128; s > 0; s >>= 1) { if (tid < s) red[tid] += red[tid+s]; __syncthreads(); }
    if (tid == 0) mp[blockIdx.x*9 + k] = red[0];
    __syncthreads();
  }
}

// ---------------- fold layer-1 BN into weights via moments ----------------
__global__ __launch_bounds__(64) void fin1_kernel(const float* __restrict__ mom, int npart,
    float Pinv, const float* __restrict__ w1, const float* __restrict__ g1,
    const float* __restrict__ be1, float* __restrict__ W1f) {
  __shared__ float M[9];
  const int t = threadIdx.x;
  if (t < 9) { float s = 0.f; for (int i = 0; i < npart; i++) s += mom[i*9 + t]; M[t] = s; }
  __syncthreads();
  const float w0 = w1[0*64 + t], w1_ = w1[1*64 + t], w2_ = w1[2*64 + t];
  const float mean = (w0*M[0] + w1_*M[1] + w2_*M[2]) * Pinv;
  const float ey2  = (w0*w0*M[3] + w1_*w1_*M[4] + w2_*w2_*M[5]
                    + 2.f*(w0*w1_*M[6] + w0*w2_*M[7] + w1_*w2_*M[8])) * Pinv;
  const float var  = fmaxf(ey2 - mean*mean, 0.f);
  const float a    = g1[t] * rsqrtf(var + BN_EPS);
  float4 r; r.x = a*w0; r.y = a*w1_; r.z = a*w2_; r.w = fmaf(-a, mean, be1[t]);
  *reinterpret_cast<float4*>(&W1f[t*4]) = r;
}

// ---------------- layer-2 BN coefficients from per-block partial sums ----------------
__global__ __launch_bounds__(128) void f2a_kernel(const float* __restrict__ partialsB, int nb,
    float Pinv, const float* __restrict__ g2, const float* __restrict__ be2,
    float* __restrict__ a2c2) {
  const int ch = threadIdx.x;
  float s = 0.f, q = 0.f;
  for (int i = 0; i < nb; i++) {
    s += partialsB[(size_t)i*512 + ch];
    q += partialsB[(size_t)i*512 + 128 + ch];
  }
  const float mean = s * Pinv;
  const float var  = fmaxf(q * Pinv - mean*mean, 0.f);
  const float a    = g2[ch] * rsqrtf(var + BN_EPS);
  a2c2[ch] = a; a2c2[128 + ch] = fmaf(-a, mean, be2[ch]);
}

// ---------------- final: maxpool(relu(BN2(y2))) via extremes ----------------
__global__ __launch_bounds__(128) void f2b_kernel(const float* __restrict__ partialsB, int bpb,
    const float* __restrict__ a2c2, float* __restrict__ out, int lv) {
  const int b = blockIdx.x, ch = threadIdx.x;
  const float* pb = partialsB + (size_t)b * bpb * 512;
  const float a = a2c2[ch], c = a2c2[128 + ch];
  float mx = -1e30f, mn = 1e30f;
  for (int i = 0; i < bpb; i++) {
    mx = fmaxf(mx, pb[(size_t)i*512 + 256 + ch]);
    mn = fminf(mn, pb[(size_t)i*512 + 384 + ch]);
  }
  const float v = (a >= 0.f) ? mx : mn;
  out[b*384 + lv*128 + ch] = fmaxf(0.f, fmaf(a, v, c));
}

// ---------------- host launch ----------------
extern "C" void kernel_launch(void* const* d_in, const int* in_sizes, int n_in,
                              void* d_out, int out_size, void* d_ws, size_t ws_size,
                              hipStream_t stream) {
  const float* pts = (const float*)d_in[0];
  const float* w1  = (const float*)d_in[1];
  const float* g1  = (const float*)d_in[3];
  const float* be1 = (const float*)d_in[4];
  const float* w2  = (const float*)d_in[5];
  const float* g2  = (const float*)d_in[7];
  const float* be2 = (const float*)d_in[8];
  float* out = (float*)d_out;
  float* wsf = (float*)d_ws;

  float* pts1 = wsf;               // 64*1024*3 = 196608
  float* pts2 = pts1 + 196608;     // 64*512*3  =  98304
  float* W1f  = pts2 + 98304;      // 256
  float* a2c2 = W1f  + 256;        // 256
  float* momP = a2c2 + 256;        // 1152 (max of 128*9, 64*9)
  float* partB= momP + 1152;       // 512*512 = 262144

  // ---- level 0 (N=2048, P=131072) ----
  mom0_kernel<<<128, 256, 0, stream>>>(pts, momP);
  fin1_kernel<<<1, 64, 0, stream>>>(momP, 128, 1.f/131072.f, w1, g1, be1, W1f);
  level_main<2048, true><<<64 + 512, 256, 0, stream>>>(pts, W1f, w2, partB, pts1, momP);
  f2a_kernel<<<1, 128, 0, stream>>>(partB, 512, 1.f/131072.f, g2, be2, a2c2);
  f2b_kernel<<<64, 128, 0, stream>>>(partB, 8, a2c2, out, 0);

  // ---- level 1 (N=1024, P=65536) ----
  fin1_kernel<<<1, 64, 0, stream>>>(momP, 64, 1.f/65536.f, w1 + 192, g1 + 64, be1 + 64, W1f);
  level_main<1024, true><<<64 + 256, 256, 0, stream>>>(pts1, W1f, w2 + 8192, partB, pts2, momP);
  f2a_kernel<<<1, 128, 0, stream>>>(partB, 256, 1.f/65536.f, g2 + 128, be2 + 128, a2c2);
  f2b_kernel<<<64, 128, 0, stream>>>(partB, 4, a2c2, out, 1);

  // ---- level 2 (N=512, P=32768, no FPS) ----
  fin1_kernel<<<1, 64, 0, stream>>>(momP, 64, 1.f/32768.f, w1 + 384, g1 + 128, be1 + 128, W1f);
  level_main<512, false><<<128, 256, 0, stream>>>(pts2, W1f, w2 + 16384, partB, wsf, wsf);
  f2a_kernel<<<1, 128, 0, stream>>>(partB, 128, 1.f/32768.f, g2 + 256, be2 + 256, a2c2);
  f2b_kernel<<<64, 128, 0, stream>>>(partB, 2, a2c2, out, 2);
}